// Round 3
// baseline (1512.254 us; speedup 1.0000x reference)
//
#include <hip/hip_runtime.h>
#include <cstdint>

#define D_MODEL 1024
#define RANK 128
#define K_RANK_ 128
#define N_KNOW 32768
#define COARSE_K 64
#define FINE_K 16
#define NTOK 4096
#define MSEL 96
#define DELTA 1.5e-3f
#define BOOT 2048
#define HALF_N 16384
#define CAP 1280

using u32 = unsigned int;
using u64 = unsigned long long;
typedef _Float16 half8 __attribute__((ext_vector_type(8)));
typedef __attribute__((ext_vector_type(4))) float f32x4;

__device__ __forceinline__ u32 ordf(float v) {
    u32 u = __float_as_uint(v);
    return (u & 0x80000000u) ? ~u : (u | 0x80000000u);
}
__device__ __forceinline__ float unordf(u32 o) {
    return (o & 0x80000000u) ? __uint_as_float(o ^ 0x80000000u)
                             : __uint_as_float(~o);
}
__device__ __forceinline__ ushort f2h(float f) {
    union { _Float16 h; ushort u; } cv; cv.h = (_Float16)f; return cv.u;
}
__device__ __forceinline__ void gload16(const void* g, void* l) {
    __builtin_amdgcn_global_load_lds(
        (const __attribute__((address_space(1))) char*)g,
        (__attribute__((address_space(3))) char*)l, 16, 0, 0);
}

// ---------------------------------------------------------------------------
// convert x -> fp16 [4096][1024]
// ---------------------------------------------------------------------------
__global__ __launch_bounds__(256)
void kcvt_x(const float* __restrict__ in, ushort* __restrict__ xh)
{
    int i = blockIdx.x * 256 + threadIdx.x;
    float4 v = ((const float4*)in)[i];
    ((ushort4*)xh)[i] = make_ushort4(f2h(v.x), f2h(v.y), f2h(v.z), f2h(v.w));
}

// ---------------------------------------------------------------------------
// transpose-convert one W half: W[k][col0+n] f32 -> wt[n][k] fp16
// ---------------------------------------------------------------------------
__global__ __launch_bounds__(256)
void kcvt_wt(const float* __restrict__ W, ushort* __restrict__ out, int col0)
{
    __shared__ float tile[32][33];
    const int nb = blockIdx.x * 32;
    const int kb = blockIdx.y * 32;
    const int tx = threadIdx.x & 31, ty = threadIdx.x >> 5;
#pragma unroll
    for (int q = 0; q < 4; ++q)
        tile[ty + q * 8][tx] = W[(size_t)(kb + ty + q * 8) * N_KNOW + col0 + nb + tx];
    __syncthreads();
#pragma unroll
    for (int q = 0; q < 4; ++q) {
        float v = tile[tx][ty + q * 8];
        out[(size_t)(nb + ty + q * 8) * D_MODEL + kb + tx] = f2h(v);
    }
}

// ---------------------------------------------------------------------------
// K1: fp16 1-pass MFMA GEMM, 128x128 tile, BK=32, 4 waves, dbuf LDS,
// global_load_lds w16, slot-XOR swizzle ((row>>1)&3) both-sides.
// MODE 0: write f32 logits to L (Lstride cols). MODE 1: fused filter —
// append keys > tau96[row] to per-token overflow list.
// ---------------------------------------------------------------------------
template <int MODE>
__global__ __launch_bounds__(256)
void k1g(const ushort* __restrict__ xh, const ushort* __restrict__ wt,
         float* __restrict__ L, int Lstride,
         u64* __restrict__ ovf, int* __restrict__ cnt,
         const u64* __restrict__ R96, int col0, int bufcol0)
{
    __shared__ ushort lds[2][8192];
    __shared__ u64 tauk[128];

    const int tid = threadIdx.x;
    const int gy = gridDim.y;
    int wfl = blockIdx.x * gy + blockIdx.y;          // col-major flat
    const int nwg = gridDim.x * gy;                  // multiple of 8
    wfl = (wfl & 7) * (nwg >> 3) + (wfl >> 3);       // XCD bijective swizzle
    const int bx = wfl / gy, by = wfl % gy;
    const int bn = bx * 128, bm = by * 128;

    const int lane = tid & 63;
    const int wv = tid >> 6;
    const int wr = wv >> 1, wc = wv & 1;
    const int lrow = lane & 15, g = lane >> 4;

    // staging: 4 chunks/thread (2 A, 2 B); inverse-swizzled global source
    const ushort* gsrc[4];
#pragma unroll
    for (int i = 0; i < 4; ++i) {
        const int o = tid + ((i & 1) << 8);            // 0..511
        const int row = o >> 2;                        // 0..127
        const int kp = (((o & 3) ^ ((o >> 3) & 3)) << 3);
        if (i < 2) gsrc[i] = xh + (size_t)(bm + row) * D_MODEL + kp;
        else       gsrc[i] = wt + (size_t)(bufcol0 + bn + row) * D_MODEL + kp;
    }

    int aoff[4], boff[4];
#pragma unroll
    for (int m = 0; m < 4; ++m) {
        int row = wr * 64 + m * 16 + lrow;
        aoff[m] = row * 32 + ((g ^ ((row >> 1) & 3)) << 3);
    }
#pragma unroll
    for (int n = 0; n < 4; ++n) {
        int row = wc * 64 + n * 16 + lrow;
        boff[n] = row * 32 + ((g ^ ((row >> 1) & 3)) << 3);
    }

    f32x4 acc[4][4];
#pragma unroll
    for (int m = 0; m < 4; ++m)
#pragma unroll
        for (int n = 0; n < 4; ++n) acc[m][n] = (f32x4)(0.f);

#pragma unroll
    for (int i = 0; i < 4; ++i)
        gload16(gsrc[i], &lds[0][(tid + (i << 8)) * 8]);
    if (MODE == 1 && tid < 128)
        tauk[tid] = R96[(size_t)(bm + tid) * MSEL + (MSEL - 1)];

    const int NKB = D_MODEL / 32;
    for (int kb = 0; kb < NKB; ++kb) {
        const int cur = kb & 1;
        __syncthreads();
        if (kb + 1 < NKB) {
#pragma unroll
            for (int i = 0; i < 4; ++i)
                gload16(gsrc[i] + (kb + 1) * 32,
                        &lds[cur ^ 1][(tid + (i << 8)) * 8]);
        }
        const ushort* lb = lds[cur];
        half8 ah[4], bh[4];
#pragma unroll
        for (int m = 0; m < 4; ++m) ah[m] = *(const half8*)(const void*)(lb + aoff[m]);
#pragma unroll
        for (int n = 0; n < 4; ++n) bh[n] = *(const half8*)(const void*)(lb + 4096 + boff[n]);
#pragma unroll
        for (int m = 0; m < 4; ++m)
#pragma unroll
            for (int n = 0; n < 4; ++n)
                acc[m][n] = __builtin_amdgcn_mfma_f32_16x16x32_f16(ah[m], bh[n], acc[m][n], 0, 0, 0);
    }

    const int crow_l = wr * 64 + (lane >> 4) * 4;
    const int ccol_l = wc * 64 + lrow;

    if (MODE == 0) {
#pragma unroll
        for (int m = 0; m < 4; ++m)
#pragma unroll
            for (int n = 0; n < 4; ++n)
#pragma unroll
                for (int r = 0; r < 4; ++r)
                    L[(size_t)(bm + crow_l + m * 16 + r) * Lstride + bn + ccol_l + n * 16] = acc[m][n][r];
    } else {
#pragma unroll
        for (int m = 0; m < 4; ++m)
#pragma unroll
            for (int n = 0; n < 4; ++n)
#pragma unroll
                for (int r = 0; r < 4; ++r) {
                    const int rl = crow_l + m * 16 + r;
                    const int gc = col0 + bn + ccol_l + n * 16;
                    u64 key = ((u64)ordf(acc[m][n][r]) << 32) | (u32)(N_KNOW - 1 - gc);
                    if (key > tauk[rl]) {
                        const int row = bm + rl;
                        int pos = atomicAdd(&cnt[row], 1);
                        if (pos < CAP) ovf[(size_t)row * CAP + pos] = key;
                    }
                }
    }
}

// ---------------------------------------------------------------------------
// K2: per-token top-M select from dense logit rows (bootstrap only)
// ---------------------------------------------------------------------------
template <int M, int VPT>
__global__ __launch_bounds__(256)
void k2_topk(const float* __restrict__ L, u64* __restrict__ R, int col0)
{
    constexpr int SC = VPT * 256;
    const int tt = blockIdx.x;
    const int tid = threadIdx.x;

    __shared__ u64 buf[4160];
    __shared__ int scnt;
    __shared__ int sred[4];

    u64 key[VPT];
    const float* row = L + (size_t)tt * SC;
#pragma unroll
    for (int j = 0; j < VPT; ++j) {
        int c = (j << 8) + tid;
        key[j] = ((u64)ordf(row[c]) << 32) | (u32)(N_KNOW - 1 - (col0 + c));
    }

    u32 lo = 0, hi = 0xFFFFFFFFu;
    for (int it = 0; it < 28; ++it) {
        if (hi - lo <= 1) break;
        u32 mid = lo + ((hi - lo) >> 1);
        int c = 0;
#pragma unroll
        for (int j = 0; j < VPT; ++j) c += ((u32)(key[j] >> 32) > mid) ? 1 : 0;
#pragma unroll
        for (int o = 32; o; o >>= 1) c += __shfl_xor(c, o);
        if ((tid & 63) == 0) sred[tid >> 6] = c;
        __syncthreads();
        c = sred[0] + sred[1] + sred[2] + sred[3];
        __syncthreads();
        if (c >= M) { lo = mid; if (c <= 768) break; }
        else hi = mid;
    }
    u64 tkey = ((u64)lo << 32) | 0xFFFFFFFFull;
    if (tid == 0) scnt = 0;
    __syncthreads();

#pragma unroll
    for (int j = 0; j < VPT; ++j)
        if (key[j] > tkey) buf[atomicAdd(&scnt, 1)] = key[j];
    __syncthreads();

    const int n = scnt;
    for (int i = tid; i < n; i += 256) {
        u64 ki = buf[i];
        int r = 0;
        for (int j = 0; j < n; ++j) r += (buf[j] > ki) ? 1 : 0;
        if (r < M) R[(size_t)tt * M + r] = ki;
    }
}

// ---------------------------------------------------------------------------
// K2m: merge R96 with overflow list -> new sorted top-96; zero cnt
// ---------------------------------------------------------------------------
__global__ __launch_bounds__(256)
void k2m(u64* __restrict__ R96, const u64* __restrict__ ovf, int* __restrict__ cnt)
{
    const int tt = blockIdx.x;
    const int tid = threadIdx.x;

    __shared__ u64 cand[MSEL + CAP];
    __shared__ u64 comp[768];
    __shared__ int scnt;
    __shared__ int sred[4];

    const int mo = min(cnt[tt], CAP);
    const int m = MSEL + mo;
    for (int i = tid; i < MSEL; i += 256) cand[i] = R96[(size_t)tt * MSEL + i];
    for (int i = tid; i < mo; i += 256) cand[MSEL + i] = ovf[(size_t)tt * CAP + i];
    __syncthreads();

    u32 lo = 0, hi = 0xFFFFFFFFu;
    for (int it = 0; it < 30; ++it) {
        if (hi - lo <= 1) break;
        u32 mid = lo + ((hi - lo) >> 1);
        int c = 0;
        for (int i = tid; i < m; i += 256) c += ((u32)(cand[i] >> 32) > mid) ? 1 : 0;
#pragma unroll
        for (int o = 32; o; o >>= 1) c += __shfl_xor(c, o);
        if ((tid & 63) == 0) sred[tid >> 6] = c;
        __syncthreads();
        c = sred[0] + sred[1] + sred[2] + sred[3];
        __syncthreads();
        if (c >= MSEL) { lo = mid; if (c <= 512) break; }
        else hi = mid;
    }
    if (tid == 0) scnt = 0;
    __syncthreads();
    for (int i = tid; i < m; i += 256)
        if ((u32)(cand[i] >> 32) > lo) {
            int p = atomicAdd(&scnt, 1);
            if (p < 768) comp[p] = cand[i];
        }
    __syncthreads();
    const int n = min(scnt, 768);
    for (int i = tid; i < n; i += 256) {
        u64 ki = comp[i];
        int r = 0;
        for (int j = 0; j < n; ++j) r += (comp[j] > ki) ? 1 : 0;
        if (r < MSEL) R96[(size_t)tt * MSEL + r] = ki;
    }
    if (tid == 0) cnt[tt] = 0;
}

// ---------------------------------------------------------------------------
// K2b: repair — exact f32 re-score of candidates within DELTA of approx 64th
// ---------------------------------------------------------------------------
__global__ __launch_bounds__(256)
void k2b_repair(const u64* __restrict__ R96, const float* __restrict__ x,
                const float* __restrict__ W, u64* __restrict__ R64)
{
    const int tt = blockIdx.x;
    const int tid = threadIdx.x;

    __shared__ u64 keys[MSEL];
    __shared__ float s[MSEL];
    __shared__ u64 nk[MSEL];
    __shared__ float xrow[D_MODEL];
    __shared__ float red[4];
    __shared__ int slo, shi;

    if (tid < MSEL) {
        keys[tid] = R96[(size_t)tt * MSEL + tid];
        s[tid] = unordf((u32)(keys[tid] >> 32));
    }
    __syncthreads();

    const float t = s[COARSE_K - 1];
    if (tid == 0) {
        int lo = 0; while (s[lo] > t + DELTA) ++lo;
        int hi = MSEL - 1; while (s[hi] < t - DELTA) --hi;
        slo = lo; shi = hi;
    }
    __syncthreads();
    const int lo = slo, hi = shi;

    if (lo == COARSE_K - 1 && hi == COARSE_K - 1) {
        if (tid < COARSE_K) R64[(size_t)tt * COARSE_K + tid] = keys[tid];
        return;
    }

    for (int i = tid; i < D_MODEL; i += 256) xrow[i] = x[(size_t)tt * D_MODEL + i];
    __syncthreads();

    for (int j = lo; j <= hi; ++j) {
        int col = (N_KNOW - 1) - (int)(u32)(keys[j] & 0xFFFFFFFFu);
        float p = 0.f;
#pragma unroll
        for (int q = 0; q < 4; ++q) {
            int k = tid + q * 256;
            p = fmaf(xrow[k], W[(size_t)k * N_KNOW + col], p);
        }
#pragma unroll
        for (int o = 32; o; o >>= 1) p += __shfl_xor(p, o);
        if ((tid & 63) == 0) red[tid >> 6] = p;
        __syncthreads();
        if (tid == 0) {
            float e = red[0] + red[1] + red[2] + red[3];
            nk[j] = ((u64)ordf(e) << 32) | (keys[j] & 0xFFFFFFFFu);
        }
        __syncthreads();
    }

    if (tid < lo) R64[(size_t)tt * COARSE_K + tid] = keys[tid];
    const int mwin = COARSE_K - lo;
    if (tid >= lo && tid <= hi) {
        u64 me = nk[tid];
        int r = 0;
        for (int j = lo; j <= hi; ++j) r += (nk[j] > me) ? 1 : 0;
        if (r < mwin) R64[(size_t)tt * COARSE_K + lo + r] = keys[tid];
    }
}

// ---------------------------------------------------------------------------
// K3a: fine scores + top-16 + softmax weights (identical arithmetic to r2 k3)
// ---------------------------------------------------------------------------
__global__ __launch_bounds__(256)
void k3a(const float* __restrict__ h, const float* __restrict__ Wq,
         const float* __restrict__ Kall, const u64* __restrict__ R,
         int* __restrict__ fidx, float* __restrict__ fw)
{
    const int tt = blockIdx.x;
    const int tid = threadIdx.x;

    __shared__ float hrow[RANK];
    __shared__ float q[K_RANK_];
    __shared__ int   cidx[COARSE_K];
    __shared__ float sc[COARSE_K];
    __shared__ int   selg[FINE_K];
    __shared__ float selsc[FINE_K];

    if (tid < RANK) hrow[tid] = h[(size_t)tt * RANK + tid];
    if (tid < COARSE_K) {
        u64 k = R[(size_t)tt * COARSE_K + tid];
        cidx[tid] = (N_KNOW - 1) - (int)(u32)(k & 0xFFFFFFFFu);
    }
    __syncthreads();

    if (tid < K_RANK_) {
        float ss = 0.f;
        const float* wr = Wq + (size_t)tid * RANK;
#pragma unroll 8
        for (int r = 0; r < RANK; ++r) ss = fmaf(hrow[r], wr[r], ss);
        q[tid] = ss;
    }
    __syncthreads();

    {
        int c = tid >> 2, part = tid & 3;
        const float* kr = Kall + (size_t)cidx[c] * K_RANK_ + part * 32;
        const float* qp = q + part * 32;
        float ss = 0.f;
#pragma unroll 8
        for (int r = 0; r < 32; ++r) ss = fmaf(qp[r], kr[r], ss);
        ss += __shfl_xor(ss, 1, 4);
        ss += __shfl_xor(ss, 2, 4);
        if (part == 0) sc[c] = ss * 0.08838834764831845f;
    }
    __syncthreads();

    if (tid < COARSE_K) {
        float v = sc[tid];
        u64 k = ((u64)ordf(v) << 32) | (u32)(63 - tid);
        int r = 0;
        for (int j = 0; j < 64; ++j) {
            u64 kj = __shfl(k, j);
            r += (kj > k) ? 1 : 0;
        }
        if (r < FINE_K) { selg[r] = cidx[tid]; selsc[r] = v; }
    }
    __syncthreads();

    if (tid < FINE_K) {
        float e = expf(selsc[tid] - selsc[0]);
        float ssum = e;
        ssum += __shfl_xor(ssum, 1, 16);
        ssum += __shfl_xor(ssum, 2, 16);
        ssum += __shfl_xor(ssum, 4, 16);
        ssum += __shfl_xor(ssum, 8, 16);
        fidx[(size_t)tt * FINE_K + tid] = selg[tid];
        fw[(size_t)tt * FINE_K + tid] = e / ssum;
    }
}

// ---------------------------------------------------------------------------
// K3b: weighted V combine
// ---------------------------------------------------------------------------
__global__ __launch_bounds__(256)
void k3b(const int* __restrict__ fidx, const float* __restrict__ fw,
         const float* __restrict__ Vall, float* __restrict__ out)
{
    const int tt = blockIdx.x;
    const int tid = threadIdx.x;
    __shared__ int sidx[FINE_K];
    __shared__ float sw_[FINE_K];
    if (tid < FINE_K) {
        sidx[tid] = fidx[(size_t)tt * FINE_K + tid];
        sw_[tid] = fw[(size_t)tt * FINE_K + tid];
    }
    __syncthreads();

    float4 o = make_float4(0.f, 0.f, 0.f, 0.f);
#pragma unroll
    for (int f = 0; f < FINE_K; ++f) {
        float wf = sw_[f];
        const float4 vv = *(const float4*)(Vall + (size_t)sidx[f] * D_MODEL + tid * 4);
        o.x = fmaf(wf, vv.x, o.x);
        o.y = fmaf(wf, vv.y, o.y);
        o.z = fmaf(wf, vv.z, o.z);
        o.w = fmaf(wf, vv.w, o.w);
    }
    *(float4*)(out + (size_t)tt * D_MODEL + tid * 4) = o;
}

// ---------------------------------------------------------------------------
extern "C" void kernel_launch(void* const* d_in, const int* in_sizes, int n_in,
                              void* d_out, int out_size, void* d_ws, size_t ws_size,
                              hipStream_t stream)
{
    const float* x  = (const float*)d_in[0];
    const float* h  = (const float*)d_in[1];
    const float* Wr = (const float*)d_in[2];
    const float* Wq = (const float*)d_in[3];
    const float* Ka = (const float*)d_in[4];
    const float* Va = (const float*)d_in[5];
    float* out = (float*)d_out;

    char* p = (char*)d_ws;
    ushort* wthi = (ushort*)p;  p += (size_t)HALF_N * D_MODEL * 2;     // 32 MB
    ushort* xh   = (ushort*)p;  p += (size_t)NTOK * D_MODEL * 2;       // 8 MB
    char*   Lovf = p;           p += (size_t)NTOK * CAP * 8;           // 40 MB (L0 32MB | ovf)
    int*    cnt  = (int*)p;     p += (size_t)NTOK * 4;
    u64*    R96  = (u64*)p;     p += (size_t)NTOK * MSEL * 8;
    u64*    R64  = (u64*)p;     p += (size_t)NTOK * COARSE_K * 8;
    int*    fidx = (int*)p;     p += (size_t)NTOK * FINE_K * 4;
    float*  fw   = (float*)p;   p += (size_t)NTOK * FINE_K * 4;
    float*  L0   = (float*)Lovf;
    u64*    ovf  = (u64*)Lovf;

    hipMemsetAsync(cnt, 0, (size_t)NTOK * 4, stream);
    kcvt_x<<<NTOK * D_MODEL / 4 / 256, 256, 0, stream>>>(x, xh);
    kcvt_wt<<<dim3(HALF_N / 32, D_MODEL / 32), 256, 0, stream>>>(Wr, wthi, 0);

    // bootstrap: dense logits for cols [0, BOOT) -> top-96
    k1g<0><<<dim3(BOOT / 128, NTOK / 128), 256, 0, stream>>>(
        xh, wthi, L0, BOOT, nullptr, nullptr, nullptr, 0, 0);
    k2_topk<MSEL, BOOT / 256><<<NTOK, 256, 0, stream>>>(L0, R96, 0);

    // fused filter: cols [BOOT, HALF_N)
    k1g<1><<<dim3((HALF_N - BOOT) / 128, NTOK / 128), 256, 0, stream>>>(
        xh, wthi, nullptr, 0, ovf, cnt, R96, BOOT, BOOT);
    k2m<<<NTOK, 256, 0, stream>>>(R96, ovf, cnt);

    // second half
    kcvt_wt<<<dim3(HALF_N / 32, D_MODEL / 32), 256, 0, stream>>>(Wr, wthi, HALF_N);
    k1g<1><<<dim3(HALF_N / 128, NTOK / 128), 256, 0, stream>>>(
        xh, wthi, nullptr, 0, ovf, cnt, R96, HALF_N, 0);
    k2m<<<NTOK, 256, 0, stream>>>(R96, ovf, cnt);

    k2b_repair<<<NTOK, 256, 0, stream>>>(R96, x, Wr, R64);
    k3a<<<NTOK, 256, 0, stream>>>(h, Wq, Ka, R64, fidx, fw);
    k3b<<<NTOK, 256, 0, stream>>>(fidx, fw, Va, out);
}

// Round 4
// 967.500 us; speedup vs baseline: 1.5631x; 1.5631x over previous
//
#include <hip/hip_runtime.h>
#include <cstdint>

#define D_MODEL 1024
#define RANK 128
#define K_RANK_ 128
#define N_KNOW 32768
#define COARSE_K 64
#define FINE_K 16
#define NTOK 4096
#define MSEL 96
#define DELTA 2.2e-3f
#define SC 4096

using u32 = unsigned int;
using u64 = unsigned long long;
typedef _Float16 half8 __attribute__((ext_vector_type(8)));
typedef __attribute__((ext_vector_type(4))) float f32x4;

__device__ __forceinline__ u32 ordf(float v) {
    u32 u = __float_as_uint(v);
    return (u & 0x80000000u) ? ~u : (u | 0x80000000u);
}
__device__ __forceinline__ float unordf(u32 o) {
    return (o & 0x80000000u) ? __uint_as_float(o ^ 0x80000000u)
                             : __uint_as_float(~o);
}
__device__ __forceinline__ ushort f2h(float f) {
    union { _Float16 h; ushort u; } cv; cv.h = (_Float16)f; return cv.u;
}
__device__ __forceinline__ void gload16(const void* g, void* l) {
    __builtin_amdgcn_global_load_lds(
        (const __attribute__((address_space(1))) char*)g,
        (__attribute__((address_space(3))) char*)l, 16, 0, 0);
}

// ---------------------------------------------------------------------------
// convert x -> fp16 [4096][1024]
// ---------------------------------------------------------------------------
__global__ __launch_bounds__(256)
void kcvt_x(const float* __restrict__ in, ushort* __restrict__ xh)
{
    int i = blockIdx.x * 256 + threadIdx.x;
    float4 v = ((const float4*)in)[i];
    ((ushort4*)xh)[i] = make_ushort4(f2h(v.x), f2h(v.y), f2h(v.z), f2h(v.w));
}

// ---------------------------------------------------------------------------
// transpose-convert one W stripe: W[k][col0+n] f32 -> wt[n][k] fp16
// ---------------------------------------------------------------------------
__global__ __launch_bounds__(256)
void kcvt_wt(const float* __restrict__ W, ushort* __restrict__ out, int col0)
{
    __shared__ float tile[32][33];
    const int nb = blockIdx.x * 32;
    const int kb = blockIdx.y * 32;
    const int tx = threadIdx.x & 31, ty = threadIdx.x >> 5;
#pragma unroll
    for (int q = 0; q < 4; ++q)
        tile[ty + q * 8][tx] = W[(size_t)(kb + ty + q * 8) * N_KNOW + col0 + nb + tx];
    __syncthreads();
#pragma unroll
    for (int q = 0; q < 4; ++q) {
        float v = tile[tx][ty + q * 8];
        out[(size_t)(nb + ty + q * 8) * D_MODEL + kb + tx] = f2h(v);
    }
}

// ---------------------------------------------------------------------------
// K1: fp16 1-pass MFMA GEMM per stripe. 128x128 tile, BK=32, 4 waves,
// dbuf LDS, global_load_lds w16, LDS slot-XOR swizzle (conflict-free, r3-
// verified), XCD-bijective block swizzle. Dense f32 logits out (stripe-local).
// ---------------------------------------------------------------------------
__global__ __launch_bounds__(256)
void k1f(const ushort* __restrict__ xh, const ushort* __restrict__ wt,
         float* __restrict__ L)
{
    __shared__ ushort lds[2][8192];   // [buf][A 128x32 | B 128x32]

    const int tid = threadIdx.x;
    const int nwg = gridDim.x * gridDim.y;           // 1024, multiple of 8
    int wfl = blockIdx.x * gridDim.y + blockIdx.y;
    wfl = (wfl & 7) * (nwg >> 3) + (wfl >> 3);       // XCD bijective swizzle
    const int bn = (wfl / (NTOK / 128)) * 128;
    const int bm = (wfl % (NTOK / 128)) * 128;

    const int lane = tid & 63;
    const int wv = tid >> 6;
    const int wr = wv >> 1, wc = wv & 1;
    const int lrow = lane & 15, g = lane >> 4;

    // staging sources (inverse-swizzled): chunk o covers row o>>2, 16B slot o&3
    const ushort* gsrc[4];
#pragma unroll
    for (int i = 0; i < 4; ++i) {
        const int o = tid + ((i & 1) << 8);            // 0..511
        const int row = o >> 2;                        // 0..127
        const int kp = (((o & 3) ^ ((o >> 3) & 3)) << 3);
        if (i < 2) gsrc[i] = xh + (size_t)(bm + row) * D_MODEL + kp;
        else       gsrc[i] = wt + (size_t)(bn + row) * D_MODEL + kp;
    }

    int aoff[4], boff[4];
#pragma unroll
    for (int m = 0; m < 4; ++m) {
        int row = wr * 64 + m * 16 + lrow;
        aoff[m] = row * 32 + ((g ^ ((row >> 1) & 3)) << 3);
    }
#pragma unroll
    for (int n = 0; n < 4; ++n) {
        int row = wc * 64 + n * 16 + lrow;
        boff[n] = row * 32 + ((g ^ ((row >> 1) & 3)) << 3);
    }

    f32x4 acc[4][4];
#pragma unroll
    for (int m = 0; m < 4; ++m)
#pragma unroll
        for (int n = 0; n < 4; ++n) acc[m][n] = (f32x4)(0.f);

#pragma unroll
    for (int i = 0; i < 4; ++i)
        gload16(gsrc[i], &lds[0][(tid + (i << 8)) * 8]);

    const int NKB = D_MODEL / 32;
    for (int kb = 0; kb < NKB; ++kb) {
        const int cur = kb & 1;
        __syncthreads();
        if (kb + 1 < NKB) {
#pragma unroll
            for (int i = 0; i < 4; ++i)
                gload16(gsrc[i] + (kb + 1) * 32,
                        &lds[cur ^ 1][(tid + (i << 8)) * 8]);
        }
        const ushort* lb = lds[cur];
        half8 ah[4], bh[4];
#pragma unroll
        for (int m = 0; m < 4; ++m) ah[m] = *(const half8*)(const void*)(lb + aoff[m]);
#pragma unroll
        for (int n = 0; n < 4; ++n) bh[n] = *(const half8*)(const void*)(lb + 4096 + boff[n]);
#pragma unroll
        for (int m = 0; m < 4; ++m)
#pragma unroll
            for (int n = 0; n < 4; ++n)
                acc[m][n] = __builtin_amdgcn_mfma_f32_16x16x32_f16(ah[m], bh[n], acc[m][n], 0, 0, 0);
    }

    const int crow = bm + wr * 64 + (lane >> 4) * 4;
    const int ccol = bn + wc * 64 + lrow;
#pragma unroll
    for (int m = 0; m < 4; ++m)
#pragma unroll
        for (int n = 0; n < 4; ++n)
#pragma unroll
            for (int r = 0; r < 4; ++r)
                L[(size_t)(crow + m * 16 + r) * SC + ccol + n * 16] = acc[m][n][r];
}

// ---------------------------------------------------------------------------
// K2: per-token running top-96 merge per stripe (r2-proven structure)
// ---------------------------------------------------------------------------
template <int M, int VPT>
__global__ __launch_bounds__(256)
void k2_topk(const float* __restrict__ L, u64* __restrict__ R,
             int col0, int stripe)
{
    const int tt = blockIdx.x;
    const int tid = threadIdx.x;

    __shared__ u64 buf[4224];
    __shared__ int scnt;
    __shared__ int sred[4];

    u64 key[VPT];
    const float* row = L + (size_t)tt * SC;
#pragma unroll
    for (int j = 0; j < VPT; ++j) {
        int c = (j << 8) + tid;
        key[j] = ((u64)ordf(row[c]) << 32) | (u32)(N_KNOW - 1 - (col0 + c));
    }

    u64 tkey;
    if (stripe == 0) {
        u32 lo = 0, hi = 0xFFFFFFFFu;
        for (int it = 0; it < 28; ++it) {
            if (hi - lo <= 1) break;
            u32 mid = lo + ((hi - lo) >> 1);
            int c = 0;
#pragma unroll
            for (int j = 0; j < VPT; ++j) c += ((u32)(key[j] >> 32) > mid) ? 1 : 0;
#pragma unroll
            for (int o = 32; o; o >>= 1) c += __shfl_xor(c, o);
            if ((tid & 63) == 0) sred[tid >> 6] = c;
            __syncthreads();
            c = sred[0] + sred[1] + sred[2] + sred[3];
            __syncthreads();
            if (c >= M) { lo = mid; if (c <= 768) break; }
            else hi = mid;
        }
        tkey = ((u64)lo << 32) | 0xFFFFFFFFull;
        if (tid == 0) scnt = 0;
    } else {
        tkey = R[(size_t)tt * M + (M - 1)];
        if (tid < M) buf[tid] = R[(size_t)tt * M + tid];
        if (tid == 0) scnt = M;
    }
    __syncthreads();

#pragma unroll
    for (int j = 0; j < VPT; ++j)
        if (key[j] > tkey) buf[atomicAdd(&scnt, 1)] = key[j];
    __syncthreads();

    const int n = scnt;
    for (int i = tid; i < n; i += 256) {
        u64 ki = buf[i];
        int r = 0;
        for (int j = 0; j < n; ++j) r += (buf[j] > ki) ? 1 : 0;
        if (r < M) R[(size_t)tt * M + r] = ki;
    }
}

// ---------------------------------------------------------------------------
// K2b: repair — exact f32 re-score of candidates within DELTA of approx 64th
// ---------------------------------------------------------------------------
__global__ __launch_bounds__(256)
void k2b_repair(const u64* __restrict__ R96, const float* __restrict__ x,
                const float* __restrict__ W, u64* __restrict__ R64)
{
    const int tt = blockIdx.x;
    const int tid = threadIdx.x;

    __shared__ u64 keys[MSEL];
    __shared__ float s[MSEL];
    __shared__ u64 nk[MSEL];
    __shared__ float xrow[D_MODEL];
    __shared__ float red[4];
    __shared__ int slo, shi;

    if (tid < MSEL) {
        keys[tid] = R96[(size_t)tt * MSEL + tid];
        s[tid] = unordf((u32)(keys[tid] >> 32));
    }
    __syncthreads();

    const float t = s[COARSE_K - 1];
    if (tid == 0) {
        int lo = 0; while (lo < COARSE_K - 1 && s[lo] > t + DELTA) ++lo;
        int hi = MSEL - 1; while (hi > COARSE_K - 1 && s[hi] < t - DELTA) --hi;
        slo = lo; shi = hi;
    }
    __syncthreads();
    const int lo = slo, hi = shi;

    if (lo == COARSE_K - 1 && hi == COARSE_K - 1) {
        if (tid < COARSE_K) R64[(size_t)tt * COARSE_K + tid] = keys[tid];
        return;
    }

    for (int i = tid; i < D_MODEL; i += 256) xrow[i] = x[(size_t)tt * D_MODEL + i];
    __syncthreads();

    for (int j = lo; j <= hi; ++j) {
        int col = (N_KNOW - 1) - (int)(u32)(keys[j] & 0xFFFFFFFFu);
        float p = 0.f;
#pragma unroll
        for (int q = 0; q < 4; ++q) {
            int k = tid + q * 256;
            p = fmaf(xrow[k], W[(size_t)k * N_KNOW + col], p);
        }
#pragma unroll
        for (int o = 32; o; o >>= 1) p += __shfl_xor(p, o);
        if ((tid & 63) == 0) red[tid >> 6] = p;
        __syncthreads();
        if (tid == 0) {
            float e = red[0] + red[1] + red[2] + red[3];
            nk[j] = ((u64)ordf(e) << 32) | (keys[j] & 0xFFFFFFFFu);
        }
        __syncthreads();
    }

    if (tid < lo) R64[(size_t)tt * COARSE_K + tid] = keys[tid];
    const int mwin = COARSE_K - lo;
    if (tid >= lo && tid <= hi) {
        u64 me = nk[tid];
        int r = 0;
        for (int j = lo; j <= hi; ++j) r += (nk[j] > me) ? 1 : 0;
        if (r < mwin) R64[(size_t)tt * COARSE_K + lo + r] = keys[tid];
    }
}

// ---------------------------------------------------------------------------
// K3a: fine scores + top-16 + softmax weights
// ---------------------------------------------------------------------------
__global__ __launch_bounds__(256)
void k3a(const float* __restrict__ h, const float* __restrict__ Wq,
         const float* __restrict__ Kall, const u64* __restrict__ R,
         int* __restrict__ fidx, float* __restrict__ fw)
{
    const int tt = blockIdx.x;
    const int tid = threadIdx.x;

    __shared__ float hrow[RANK];
    __shared__ float q[K_RANK_];
    __shared__ int   cidx[COARSE_K];
    __shared__ float sc[COARSE_K];
    __shared__ int   selg[FINE_K];
    __shared__ float selsc[FINE_K];

    if (tid < RANK) hrow[tid] = h[(size_t)tt * RANK + tid];
    if (tid < COARSE_K) {
        u64 k = R[(size_t)tt * COARSE_K + tid];
        cidx[tid] = (N_KNOW - 1) - (int)(u32)(k & 0xFFFFFFFFu);
    }
    __syncthreads();

    if (tid < K_RANK_) {
        float ss = 0.f;
        const float* wr = Wq + (size_t)tid * RANK;
#pragma unroll 8
        for (int r = 0; r < RANK; ++r) ss = fmaf(hrow[r], wr[r], ss);
        q[tid] = ss;
    }
    __syncthreads();

    {
        int c = tid >> 2, part = tid & 3;
        const float* kr = Kall + (size_t)cidx[c] * K_RANK_ + part * 32;
        const float* qp = q + part * 32;
        float ss = 0.f;
#pragma unroll 8
        for (int r = 0; r < 32; ++r) ss = fmaf(qp[r], kr[r], ss);
        ss += __shfl_xor(ss, 1, 4);
        ss += __shfl_xor(ss, 2, 4);
        if (part == 0) sc[c] = ss * 0.08838834764831845f;
    }
    __syncthreads();

    if (tid < COARSE_K) {
        float v = sc[tid];
        u64 k = ((u64)ordf(v) << 32) | (u32)(63 - tid);
        int r = 0;
        for (int j = 0; j < 64; ++j) {
            u64 kj = __shfl(k, j);
            r += (kj > k) ? 1 : 0;
        }
        if (r < FINE_K) { selg[r] = cidx[tid]; selsc[r] = v; }
    }
    __syncthreads();

    if (tid < FINE_K) {
        float e = expf(selsc[tid] - selsc[0]);
        float ssum = e;
        ssum += __shfl_xor(ssum, 1, 16);
        ssum += __shfl_xor(ssum, 2, 16);
        ssum += __shfl_xor(ssum, 4, 16);
        ssum += __shfl_xor(ssum, 8, 16);
        fidx[(size_t)tt * FINE_K + tid] = selg[tid];
        fw[(size_t)tt * FINE_K + tid] = e / ssum;
    }
}

// ---------------------------------------------------------------------------
// K3b: weighted V combine
// ---------------------------------------------------------------------------
__global__ __launch_bounds__(256)
void k3b(const int* __restrict__ fidx, const float* __restrict__ fw,
         const float* __restrict__ Vall, float* __restrict__ out)
{
    const int tt = blockIdx.x;
    const int tid = threadIdx.x;
    __shared__ int sidx[FINE_K];
    __shared__ float sw_[FINE_K];
    if (tid < FINE_K) {
        sidx[tid] = fidx[(size_t)tt * FINE_K + tid];
        sw_[tid] = fw[(size_t)tt * FINE_K + tid];
    }
    __syncthreads();

    float4 o = make_float4(0.f, 0.f, 0.f, 0.f);
#pragma unroll
    for (int f = 0; f < FINE_K; ++f) {
        float wf = sw_[f];
        const float4 vv = *(const float4*)(Vall + (size_t)sidx[f] * D_MODEL + tid * 4);
        o.x = fmaf(wf, vv.x, o.x);
        o.y = fmaf(wf, vv.y, o.y);
        o.z = fmaf(wf, vv.z, o.z);
        o.w = fmaf(wf, vv.w, o.w);
    }
    *(float4*)(out + (size_t)tt * D_MODEL + tid * 4) = o;
}

// ---------------------------------------------------------------------------
extern "C" void kernel_launch(void* const* d_in, const int* in_sizes, int n_in,
                              void* d_out, int out_size, void* d_ws, size_t ws_size,
                              hipStream_t stream)
{
    const float* x  = (const float*)d_in[0];
    const float* h  = (const float*)d_in[1];
    const float* Wr = (const float*)d_in[2];
    const float* Wq = (const float*)d_in[3];
    const float* Ka = (const float*)d_in[4];
    const float* Va = (const float*)d_in[5];
    float* out = (float*)d_out;

    char* p = (char*)d_ws;
    ushort* wt   = (ushort*)p;  p += (size_t)SC * D_MODEL * 2;         // 8 MB
    ushort* xh   = (ushort*)p;  p += (size_t)NTOK * D_MODEL * 2;       // 8 MB
    float*  L    = (float*)p;   p += (size_t)NTOK * SC * 4;            // 64 MB
    u64*    R96  = (u64*)p;     p += (size_t)NTOK * MSEL * 8;          // 3 MB
    u64*    R64  = (u64*)p;     p += (size_t)NTOK * COARSE_K * 8;      // 2 MB
    int*    fidx = (int*)p;     p += (size_t)NTOK * FINE_K * 4;
    float*  fw   = (float*)p;   p += (size_t)NTOK * FINE_K * 4;

    kcvt_x<<<NTOK * D_MODEL / 4 / 256, 256, 0, stream>>>(x, xh);

    const int nstripe = N_KNOW / SC;
    for (int s = 0; s < nstripe; ++s) {
        kcvt_wt<<<dim3(SC / 32, D_MODEL / 32), 256, 0, stream>>>(Wr, wt, s * SC);
        k1f<<<dim3(SC / 128, NTOK / 128), 256, 0, stream>>>(xh, wt, L);
        k2_topk<MSEL, SC / 256><<<NTOK, 256, 0, stream>>>(L, R96, s * SC, s);
    }
    k2b_repair<<<NTOK, 256, 0, stream>>>(R96, x, Wr, R64);
    k3a<<<NTOK, 256, 0, stream>>>(h, Wq, Ka, R64, fidx, fw);
    k3b<<<NTOK, 256, 0, stream>>>(fidx, fw, Va, out);
}